// Round 12
// baseline (196.226 us; speedup 1.0000x reference)
//
#include <hip/hip_runtime.h>

#define B_   4
#define S_   2048
#define HID  512
#define H_   8
#define HD   64

typedef __attribute__((ext_vector_type(8))) short bf16x8;
typedef __attribute__((ext_vector_type(4))) float f32x4;

#define MFMA16(a, b, c) __builtin_amdgcn_mfma_f32_16x16x32_bf16(a, b, c, 0, 0, 0)

#define GAMMA_L0   (-3.4657359027997265f)
#define GAMMA_STEP (-0.3960841031771116f)

__device__ __forceinline__ void async16(const void* g, void* l) {
    __builtin_amdgcn_global_load_lds(
        (const __attribute__((address_space(1))) void*)g,
        (__attribute__((address_space(3))) void*)l, 16, 0, 0);
}

__device__ __forceinline__ unsigned short f2bf(float x) {
    unsigned u = __float_as_uint(x);
    return (unsigned short)((u + 0x7fffu + ((u >> 16) & 1u)) >> 16);
}
__device__ __forceinline__ float bfs2f(short s) {
    return __uint_as_float(((unsigned)(unsigned short)s) << 16);
}
__device__ __forceinline__ unsigned packbf(float lo, float hi) {
    return (unsigned)f2bf(lo) | ((unsigned)f2bf(hi) << 16);
}

// ---------------------------------------------------------------------------
// prep: blocks [0,2048) convert X fp32->bf16; [2048,2368) transpose weights;
// [2368,2624) xPos LUT {cos*sc, sin*sc, cos/sc, sin/sc}.
// ---------------------------------------------------------------------------
__global__ __launch_bounds__(256) void prep(
    const float* __restrict__ X,
    const float* __restrict__ Wq, const float* __restrict__ Wk,
    const float* __restrict__ Wv, const float* __restrict__ Wg,
    const float* __restrict__ Wo,
    short* __restrict__ Xb,
    short* __restrict__ WqT, short* __restrict__ WkT, short* __restrict__ WvT,
    short* __restrict__ WgT, short* __restrict__ WoT,
    float4* __restrict__ Lut)
{
    __shared__ float T[64][65];
    const int bid = blockIdx.x, t = threadIdx.x;

    if (bid < 2048) {
        size_t i = ((size_t)bid * 256 + t) * 8;
        float4 a = *(const float4*)&X[i];
        float4 b = *(const float4*)&X[i + 4];
        union { int4 v; unsigned short s[8]; } u;
        u.s[0] = f2bf(a.x); u.s[1] = f2bf(a.y); u.s[2] = f2bf(a.z); u.s[3] = f2bf(a.w);
        u.s[4] = f2bf(b.x); u.s[5] = f2bf(b.y); u.s[6] = f2bf(b.z); u.s[7] = f2bf(b.w);
        *(int4*)&Xb[i] = u.v;
        return;
    }
    if (bid >= 2368) {
        int idx = (bid - 2368) * 256 + t;   // 65536 = 2048*32
        int s = idx >> 5, k = idx & 31;
        float invf = exp2f(-0.41524101186092035f * (float)k);  // 10000^(-k/32)
        float ang  = (float)s * invf;
        float sn = sinf(ang), cs = cosf(ang);
        float sk = ((float)(2 * k) + 25.6f) / 89.6f;
        float sc = exp2f(log2f(sk) * (float)s * (1.0f / 512.0f));
        Lut[idx] = (float4){cs * sc, sn * sc, cs / sc, sn / sc};
        return;
    }

    const int wb = bid - 2048;
    const float* ip; short* op; int ild;
    if (wb < 192) {
        int which = wb >> 6, rem = wb & 63, h = rem >> 3, kt = rem & 7;
        const float* src = which == 0 ? Wq : which == 1 ? Wk : Wv;
        short* dst       = which == 0 ? WqT : which == 1 ? WkT : WvT;
        ip = src + ((size_t)h * 512 + kt * 64) * 64;
        ild = 64;
        op = dst + (size_t)(h * 64) * 512 + kt * 64;
    } else {
        int rem = wb - 192, which = rem >> 6, r3 = rem & 63, nt = r3 >> 3, kt = r3 & 7;
        const float* src = which ? Wo : Wg;
        short* dst       = which ? WoT : WgT;
        ip = src + (size_t)(kt * 64) * 512 + nt * 64;
        ild = 512;
        op = dst + (size_t)(nt * 64) * 512 + kt * 64;
    }
    {
        int r = t >> 2, c0 = (t & 3) * 16;
        #pragma unroll
        for (int e = 0; e < 4; ++e) {
            float4 f = *(const float4*)&ip[(size_t)r * ild + c0 + e * 4];
            T[r][c0 + e*4 + 0] = f.x; T[r][c0 + e*4 + 1] = f.y;
            T[r][c0 + e*4 + 2] = f.z; T[r][c0 + e*4 + 3] = f.w;
        }
    }
    __syncthreads();
    {
        int cc = t >> 2, r0 = (t & 3) * 16;
        short* orow = op + (size_t)cc * 512;
        #pragma unroll
        for (int ii = 0; ii < 8; ++ii) {
            int lo = f2bf(T[r0 + 2*ii][cc]);
            int hi = f2bf(T[r0 + 2*ii + 1][cc]);
            *(int*)(orow + r0 + 2*ii) = (lo & 0xffff) | (hi << 16);
        }
    }
}

// ---------------------------------------------------------------------------
// 64x128 bf16 MFMA GEMM core, BK=64, single buffer, XOR swizzle
// (idx&7)^(row&7). LDS: A 4096 shorts @0, B 8192 shorts @4096 = 24576 B.
// ---------------------------------------------------------------------------
__device__ __forceinline__ void stage64k(const short* __restrict__ Ag,
                                         const short* __restrict__ Bg,
                                         int k0, short* As, short* Bs, int tid)
{
    #pragma unroll
    for (int j = 0; j < 2; ++j) {          // A: 64 rows x 8 slots
        int idx = j * 256 + tid;
        int row = idx >> 3, c8 = (idx & 7) ^ (row & 7);
        async16(Ag + (size_t)row * 512 + k0 + c8 * 8, As + idx * 8);
    }
    #pragma unroll
    for (int j = 0; j < 4; ++j) {          // B: 128 rows x 8 slots
        int idx = j * 256 + tid;
        int row = idx >> 3, c8 = (idx & 7) ^ (row & 7);
        async16(Bg + (size_t)row * 512 + k0 + c8 * 8, Bs + idx * 8);
    }
}

__device__ __forceinline__ void gemm_core64(const short* __restrict__ Ag,
                                            const short* __restrict__ Bg,
                                            short* SM, f32x4 (&acc)[2][4])
{
    const int tid = threadIdx.x;
    const int L = tid & 63, quad = L >> 4, l16 = L & 15;
    const int w = tid >> 6;
    const int wrow = (w >> 1) * 32, wcol = (w & 1) * 64;
    short* As = SM;
    short* Bs = SM + 4096;

    for (int k0 = 0; k0 < 512; k0 += 64) {
        stage64k(Ag, Bg, k0, As, Bs, tid);
        __syncthreads();
        #pragma unroll
        for (int ks = 0; ks < 2; ++ks) {
            bf16x8 af[2], bfr[4];
            #pragma unroll
            for (int a = 0; a < 2; ++a) {
                int m = wrow + a * 16 + l16;
                af[a] = *(const bf16x8*)&As[m * 64 + ((quad + 4 * ks) ^ (m & 7)) * 8];
            }
            #pragma unroll
            for (int b = 0; b < 4; ++b) {
                int n = wcol + b * 16 + l16;
                bfr[b] = *(const bf16x8*)&Bs[n * 64 + ((quad + 4 * ks) ^ (n & 7)) * 8];
            }
            #pragma unroll
            for (int a = 0; a < 2; ++a)
                #pragma unroll
                for (int b = 0; b < 4; ++b)
                    acc[a][b] = MFMA16(af[a], bfr[b], acc[a][b]);
        }
        __syncthreads();
    }
}

// ---------------------------------------------------------------------------
// Fused QKV+Gate GEMM: grid (128, 16), M-tile fastest (XCD locality).
// zone = bx>>2: 0=Q (xPos+), 1=K (xPos-), 2=V, 3=Gate (SiLU).
// ---------------------------------------------------------------------------
__global__ __launch_bounds__(256) void fused_gemm(
    const short* __restrict__ Xb, const short* __restrict__ WT,
    const float4* __restrict__ Lut,
    short* __restrict__ Qb, short* __restrict__ Kb, short* __restrict__ Vb,
    short* __restrict__ Gb)
{
    __shared__ short SM[12288];   // staging 24576 B; repack 64x136 fits
    const int by = blockIdx.x;    // M-tile 0..127 (fastest)
    const int bx = blockIdx.y;    // N-tile 0..15

    f32x4 acc[2][4];
    #pragma unroll
    for (int a = 0; a < 2; ++a)
        #pragma unroll
        for (int b = 0; b < 4; ++b) acc[a][b] = (f32x4){0.f, 0.f, 0.f, 0.f};

    gemm_core64(Xb + (size_t)by * 64 * 512,
                WT + (size_t)bx * 128 * 512, SM, acc);

    const int tid = threadIdx.x, L = tid & 63, quad = L >> 4, l16 = L & 15;
    const int w = tid >> 6, wrow = (w >> 1) * 32, wcol = (w & 1) * 64;
    const int zone = bx >> 2;
    short* Out = (zone == 0) ? Qb : (zone == 1) ? Kb : Vb;

    #pragma unroll
    for (int b = 0; b < 4; ++b) {
        int ncol = (bx & 3) * 128 + wcol + b * 16 + l16;
        int d = ncol & 63, k = d >> 1;
        int colE = wcol + b * 16 + (l16 & ~1);
        #pragma unroll
        for (int a = 0; a < 2; ++a) {
            #pragma unroll
            for (int r = 0; r < 4; ++r) {
                int m = by * 64 + wrow + a * 16 + quad * 4 + r;
                int s = m & 2047;
                float v = acc[a][b][r];
                unsigned word;
                if (zone == 3) {
                    float g = v / (1.0f + __expf(-v));
                    float part = __shfl_xor(g, 1);
                    word = packbf(g, part);
                } else {
                    float part = __shfl_xor(v, 1);
                    float e = (d & 1) ? part : v;
                    float o = (d & 1) ? v : part;
                    if (zone == 2) {
                        word = packbf(e, o);
                    } else {
                        float4 f = Lut[s * 32 + k];
                        float cs = (zone == 0) ? f.x : f.z;
                        float sn = (zone == 0) ? f.y : f.w;
                        word = packbf(e * cs - o * sn, o * cs + e * sn);
                    }
                }
                if (!(l16 & 1))
                    *(int*)&SM[(wrow + a * 16 + quad * 4 + r) * 136 + colE] = word;
            }
        }
    }
    __syncthreads();
    #pragma unroll
    for (int j = 0; j < 4; ++j) {
        int idx = j * 256 + tid;
        int row = idx >> 4, c0 = (idx & 15) * 8;
        int m = by * 64 + row;
        int n = (bx & 3) * 128 + c0;
        if (zone == 3) {
            *(int4*)&Gb[(size_t)m * 512 + n] = *(const int4*)&SM[row * 136 + c0];
        } else {
            int bb = m >> 11, s = m & 2047;
            int h = n >> 6, d = n & 63;
            *(int4*)&Out[(((size_t)bb * 8 + h) * 2048 + s) * 64 + d] =
                *(const int4*)&SM[row * 136 + c0];
        }
    }
}

// ---------------------------------------------------------------------------
// Output GEMM: out = Z @ W_O, fp32 out. 64x64 tiles, BK=64, grid (128, 8):
// 1024 blocks = 4/CU assigned, all co-resident (LDS 16 KB). M-tile fastest.
// ---------------------------------------------------------------------------
__global__ __launch_bounds__(256) void out_gemm(
    const short* __restrict__ Zb, const short* __restrict__ WoT,
    float* __restrict__ Of)
{
    __shared__ short SM[8192];    // A 4096 + B 4096 shorts = 16 KB
    const int by = blockIdx.x;    // M-tile 0..127 (fastest)
    const int bx = blockIdx.y;    // N-tile 0..7

    f32x4 acc[2][2];
    #pragma unroll
    for (int a = 0; a < 2; ++a)
        #pragma unroll
        for (int b = 0; b < 2; ++b) acc[a][b] = (f32x4){0.f, 0.f, 0.f, 0.f};

    const int tid = threadIdx.x;
    const int L = tid & 63, quad = L >> 4, l16 = L & 15;
    const int w = tid >> 6;
    const int wrow = (w >> 1) * 32, wcol = (w & 1) * 32;
    const short* Ag = Zb + (size_t)by * 64 * 512;
    const short* Bg = WoT + (size_t)bx * 64 * 512;
    short* As = SM;
    short* Bs = SM + 4096;

    for (int k0 = 0; k0 < 512; k0 += 64) {
        #pragma unroll
        for (int j = 0; j < 2; ++j) {
            int idx = j * 256 + tid;
            int row = idx >> 3, c8 = (idx & 7) ^ (row & 7);
            async16(Ag + (size_t)row * 512 + k0 + c8 * 8, As + idx * 8);
            async16(Bg + (size_t)row * 512 + k0 + c8 * 8, Bs + idx * 8);
        }
        __syncthreads();
        #pragma unroll
        for (int ks = 0; ks < 2; ++ks) {
            bf16x8 af[2], bfr[2];
            #pragma unroll
            for (int a = 0; a < 2; ++a) {
                int m = wrow + a * 16 + l16;
                af[a] = *(const bf16x8*)&As[m * 64 + ((quad + 4 * ks) ^ (m & 7)) * 8];
            }
            #pragma unroll
            for (int b = 0; b < 2; ++b) {
                int n = wcol + b * 16 + l16;
                bfr[b] = *(const bf16x8*)&Bs[n * 64 + ((quad + 4 * ks) ^ (n & 7)) * 8];
            }
            #pragma unroll
            for (int a = 0; a < 2; ++a)
                #pragma unroll
                for (int b = 0; b < 2; ++b)
                    acc[a][b] = MFMA16(af[a], bfr[b], acc[a][b]);
        }
        __syncthreads();
    }

    #pragma unroll
    for (int b = 0; b < 2; ++b) {
        int ncol = bx * 64 + wcol + b * 16 + l16;
        #pragma unroll
        for (int a = 0; a < 2; ++a)
            #pragma unroll
            for (int r = 0; r < 4; ++r) {
                int m = by * 64 + wrow + a * 16 + quad * 4 + r;
                Of[(size_t)m * 512 + ncol] = acc[a][b][r];
            }
    }
}

// ---------------------------------------------------------------------------
// Retention G+scan merged: one block per bn. State M (64x64) lives in
// registers (C-layout, 16 fp32/lane). Loop c = 0..31:
//   write M_c (pre-update, bf16) -> Mb; G_c = V^T diag(gamma^(64-jl)) K;
//   M = gamma^64 * M + G_c.  VGPR prefetch of chunk c+1 overlaps MFMA.
// ---------------------------------------------------------------------------
__global__ __launch_bounds__(256) void ret_gm(
    const short* __restrict__ Kb, const short* __restrict__ Vb,
    short* __restrict__ Mb)
{
    __shared__ short Kt[64 * 72];
    __shared__ short Vt[64 * 72];
    const int tid = threadIdx.x, L = tid & 63, quad = L >> 4, l16 = L & 15;
    const int w = tid >> 6;
    const int bn = blockIdx.x, hh = bn & 7;

    float gamma = 1.0f - expf(GAMMA_L0 + GAMMA_STEP * (float)hh);
    float lg = log2f(gamma);
    float g64 = exp2f(lg * 64.0f);
    float wgt = exp2f(lg * (float)(64 - L));   // per-jl K weight

    const short* Kbase = Kb + ((size_t)bn * 2048 + L) * 64 + w * 16;
    const short* Vbase = Vb + ((size_t)bn * 2048 + L) * 64 + w * 16;

    f32x4 M[4];
    #pragma unroll
    for (int b = 0; b < 4; ++b) M[b] = (f32x4){0.f, 0.f, 0.f, 0.f};

    int4 k0 = *(const int4*)Kbase;      int4 k1 = *(const int4*)(Kbase + 8);
    int4 v0 = *(const int4*)Vbase;      int4 v1 = *(const int4*)(Vbase + 8);

    for (int c = 0; c < 32; ++c) {
        __syncthreads();   // prior iteration's Kt/Vt reads done
        {
            short* kt = Kt + L; short* vt = Vt + L;
            #pragma unroll
            for (int q = 0; q < 4; ++q) {
                int uk = ((const int*)&k0)[q];
                kt[(w*16 + 2*q)     * 72] = (short)f2bf(bfs2f((short)uk) * wgt);
                kt[(w*16 + 2*q + 1) * 72] = (short)f2bf(bfs2f((short)(uk >> 16)) * wgt);
                int uv = ((const int*)&v0)[q];
                vt[(w*16 + 2*q)     * 72] = (short)uv;
                vt[(w*16 + 2*q + 1) * 72] = (short)(uv >> 16);
            }
            #pragma unroll
            for (int q = 0; q < 4; ++q) {
                int uk = ((const int*)&k1)[q];
                kt[(w*16 + 8 + 2*q) * 72] = (short)f2bf(bfs2f((short)uk) * wgt);
                kt[(w*16 + 9 + 2*q) * 72] = (short)f2bf(bfs2f((short)(uk >> 16)) * wgt);
                int uv = ((const int*)&v1)[q];
                vt[(w*16 + 8 + 2*q) * 72] = (short)uv;
                vt[(w*16 + 9 + 2*q) * 72] = (short)(uv >> 16);
            }
        }
        __syncthreads();

        if (c + 1 < 32) {   // prefetch next chunk into VGPRs (overlaps MFMA)
            const short* kn = Kbase + (size_t)(c + 1) * 64 * 64;
            const short* vn = Vbase + (size_t)(c + 1) * 64 * 64;
            k0 = *(const int4*)kn; k1 = *(const int4*)(kn + 8);
            v0 = *(const int4*)vn; v1 = *(const int4*)(vn + 8);
        }

        // write M_c (pre-update)
        short* Mp = Mb + ((size_t)bn * 32 + c) * 4096;
        #pragma unroll
        for (int b = 0; b < 4; ++b) {
            #pragma unroll
            for (int r = 0; r < 4; ++r) {
                float v = M[b][r];
                float part = __shfl_xor(v, 1);
                unsigned word = packbf(v, part);
                if (!(l16 & 1))
                    *(int*)&Mp[(w*16 + quad*4 + r) * 64 + b * 16 + (l16 & ~1)] = word;
            }
        }

        // G_c and state update
        bf16x8 a0 = *(const bf16x8*)&Vt[(w * 16 + l16) * 72 + quad * 8];
        bf16x8 a1 = *(const bf16x8*)&Vt[(w * 16 + l16) * 72 + 32 + quad * 8];
        #pragma unroll
        for (int b = 0; b < 4; ++b) {
            bf16x8 b0 = *(const bf16x8*)&Kt[(b * 16 + l16) * 72 + quad * 8];
            bf16x8 b1 = *(const bf16x8*)&Kt[(b * 16 + l16) * 72 + 32 + quad * 8];
            f32x4 accG = (f32x4){0.f, 0.f, 0.f, 0.f};
            accG = MFMA16(a0, b0, accG);
            accG = MFMA16(a1, b1, accG);
            #pragma unroll
            for (int r = 0; r < 4; ++r)
                M[b][r] = g64 * M[b][r] + accG[r];
        }
    }
}

// ---------------------------------------------------------------------------
// Retention main + fused GroupNorm/gate:
//   Y = (QK^T . gamma^|i-j|) V + gamma^il (Q M_c)   [fp32 in regs]
//   Z = silu_gate * ((Y - mu)/sqrt(var+eps) * gw + gb)   -> Zb bf16 [8192][512]
// ---------------------------------------------------------------------------
__global__ __launch_bounds__(256) void ret_main(
    const short* __restrict__ Qb, const short* __restrict__ Kb,
    const short* __restrict__ Vb, const short* __restrict__ Mb,
    const short* __restrict__ Gb,
    const float* __restrict__ gw, const float* __restrict__ gb,
    short* __restrict__ Zb)
{
    __shared__ short Qs[4096];
    __shared__ short Ks[4096];
    __shared__ short Ms[4096];
    __shared__ short Vt[64 * 72];
    __shared__ short Pw[4][16 * 72];

    const int tid = threadIdx.x, L = tid & 63, quad = L >> 4, l16 = L & 15;
    const int w = tid >> 6;
    const int c = blockIdx.x, bn = blockIdx.y, hh = bn & 7, bb = bn >> 3;

    float gamma = 1.0f - expf(GAMMA_L0 + GAMMA_STEP * (float)hh);
    float lg = log2f(gamma);

    float Dabs[4][4];
    #pragma unroll
    for (int b = 0; b < 4; ++b)
        #pragma unroll
        for (int r = 0; r < 4; ++r) {
            int dlt = (w * 16 + quad * 4 + r) - (b * 16 + l16);
            Dabs[b][r] = exp2f(lg * fabsf((float)dlt));
        }
    float gq[4];
    #pragma unroll
    for (int r = 0; r < 4; ++r)
        gq[r] = exp2f(lg * (float)(w * 16 + quad * 4 + r));

    {
        const short* qg = Qb + ((size_t)bn * 2048 + c * 64 + w * 16 + (L >> 2)) * 64 + (L & 3) * 8;
        async16(qg,      Qs + w * 512 + L * 8);
        async16(qg + 32, Qs + 2048 + w * 512 + L * 8);
        const short* kg = Kb + ((size_t)bn * 2048 + c * 64 + w * 16 + (L >> 2)) * 64 + (L & 3) * 8;
        async16(kg,      Ks + w * 512 + L * 8);
        async16(kg + 32, Ks + 2048 + w * 512 + L * 8);
        const short* mg = Mb + ((size_t)bn * 32 + c) * 4096 + (w * 16 + (L >> 2)) * 64 + (L & 3) * 8;
        async16(mg,      Ms + w * 512 + L * 8);
        async16(mg + 32, Ms + 2048 + w * 512 + L * 8);
    }
    {
        const short* vg = Vb + ((size_t)bn * 2048 + c * 64 + L) * 64 + w * 16;
        int4 v0 = *(const int4*)vg;
        int4 v1 = *(const int4*)(vg + 8);
        short* vt = Vt + L;
        #pragma unroll
        for (int q = 0; q < 4; ++q) {
            int u = ((const int*)&v0)[q];
            vt[(w*16 + 2*q)     * 72] = (short)u;
            vt[(w*16 + 2*q + 1) * 72] = (short)(u >> 16);
        }
        #pragma unroll
        for (int q = 0; q < 4; ++q) {
            int u = ((const int*)&v1)[q];
            vt[(w*16 + 8 + 2*q) * 72] = (short)u;
            vt[(w*16 + 9 + 2*q) * 72] = (short)(u >> 16);
        }
    }
    __syncthreads();

    bf16x8 aQ0 = *(const bf16x8*)&Qs[(w * 16 + l16) * 32 + quad * 8];
    bf16x8 aQ1 = *(const bf16x8*)&Qs[2048 + (w * 16 + l16) * 32 + quad * 8];
    f32x4 accM[4];
    #pragma unroll
    for (int b = 0; b < 4; ++b) {
        bf16x8 k0 = *(const bf16x8*)&Ks[(b * 16 + l16) * 32 + quad * 8];
        bf16x8 k1 = *(const bf16x8*)&Ks[2048 + (b * 16 + l16) * 32 + quad * 8];
        f32x4 S = (f32x4){0.f, 0.f, 0.f, 0.f};
        S = MFMA16(aQ0, k0, S);
        S = MFMA16(aQ1, k1, S);
        #pragma unroll
        for (int r = 0; r < 4; ++r)
            Pw[w][(quad * 4 + r) * 72 + b * 16 + l16] = (short)f2bf(S[r] * Dabs[b][r]);

        bf16x8 m0 = *(const bf16x8*)&Ms[(b * 16 + l16) * 32 + quad * 8];
        bf16x8 m1 = *(const bf16x8*)&Ms[2048 + (b * 16 + l16) * 32 + quad * 8];
        f32x4 Mv = (f32x4){0.f, 0.f, 0.f, 0.f};
        Mv = MFMA16(aQ0, m0, Mv);
        Mv = MFMA16(aQ1, m1, Mv);
        accM[b] = Mv;
    }

    bf16x8 aP0 = *(const bf16x8*)&Pw[w][l16 * 72 + quad * 8];
    bf16x8 aP1 = *(const bf16x8*)&Pw[w][l16 * 72 + 32 + quad * 8];
    f32x4 Y4[4];
    #pragma unroll
    for (int b2 = 0; b2 < 4; ++b2) {
        bf16x8 v0f = *(const bf16x8*)&Vt[(b2 * 16 + l16) * 72 + quad * 8];
        bf16x8 v1f = *(const bf16x8*)&Vt[(b2 * 16 + l16) * 72 + 32 + quad * 8];
        f32x4 yv = (f32x4){0.f, 0.f, 0.f, 0.f};
        yv = MFMA16(aP0, v0f, yv);
        yv = MFMA16(aP1, v1f, yv);
        #pragma unroll
        for (int r = 0; r < 4; ++r)
            Y4[b2][r] = yv[r] + gq[r] * accM[b2][r];
    }

    #pragma unroll
    for (int r = 0; r < 4; ++r) {
        float s1 = 0.f, s2 = 0.f;
        #pragma unroll
        for (int b2 = 0; b2 < 4; ++b2) {
            float v = Y4[b2][r];
            s1 += v; s2 += v * v;
        }
        #pragma unroll
        for (int off = 1; off < 16; off <<= 1) {
            s1 += __shfl_xor(s1, off);
            s2 += __shfl_xor(s2, off);
        }
        float mu = s1 * (1.0f / 64.0f);
        float var = s2 * (1.0f / 64.0f) - mu * mu;
        float rstd = rsqrtf(var + 1e-5f);

        int il = w * 16 + quad * 4 + r;
        size_t row = (size_t)bb * 2048 + c * 64 + il;
        #pragma unroll
        for (int b2 = 0; b2 < 4; ++b2) {
            int j = hh * 64 + b2 * 16 + l16;
            float yn = (Y4[b2][r] - mu) * rstd * gw[j] + gb[j];
            float z = bfs2f(Gb[row * 512 + j]) * yn;
            float part = __shfl_xor(z, 1);
            if (!(l16 & 1))
                *(int*)&Zb[row * 512 + hh * 64 + b2 * 16 + (l16 & ~1)] = packbf(z, part);
        }
    }
}

// ---------------------------------------------------------------------------
extern "C" void kernel_launch(void* const* d_in, const int* in_sizes, int n_in,
                              void* d_out, int out_size, void* d_ws, size_t ws_size,
                              hipStream_t stream)
{
    const float* X  = (const float*)d_in[0];
    const float* Wq = (const float*)d_in[1];
    const float* Wk = (const float*)d_in[2];
    const float* Wv = (const float*)d_in[3];
    const float* Wg = (const float*)d_in[4];
    const float* Wo = (const float*)d_in[5];
    const float* gw = (const float*)d_in[6];
    const float* gb = (const float*)d_in[7];

    char* ws = (char*)d_ws;
    short* Xb  = (short*)ws;                          // 8,388,608 B
    short* WqT = (short*)(ws + 8388608);              // 512 KB each: Q,K,V,G,O
    short* WkT = WqT + 262144;
    short* WvT = WkT + 262144;
    short* WgT = WvT + 262144;
    short* WoT = WgT + 262144;
    short* Qb  = (short*)(ws + 11010048);             // 8,388,608 B each
    short* Kb  = Qb + 4194304;
    short* Vb  = Kb + 4194304;
    float4* Lut = (float4*)(ws + 36175872);           // 1,048,576 B
    short* GM  = (short*)(ws + 37224448);             // 8,388,608 B (M states)
    short* Zb  = (short*)(ws + 45613056);             // 8,388,608 B
    short* Gb  = (short*)(ws + 54001664);             // 8,388,608 B (ends 62,390,272)

    prep<<<2624, 256, 0, stream>>>(X, Wq, Wk, Wv, Wg, Wo,
                                   Xb, WqT, WkT, WvT, WgT, WoT, Lut);
    fused_gemm<<<dim3(128, 16), 256, 0, stream>>>(Xb, WqT, Lut, Qb, Kb, Vb, Gb);
    ret_gm<<<dim3(32), 256, 0, stream>>>(Kb, Vb, GM);
    ret_main<<<dim3(32, 32), 256, 0, stream>>>(Qb, Kb, Vb, GM, Gb, gw, gb, Zb);
    out_gemm<<<dim3(128, 8), 256, 0, stream>>>(Zb, WoT, (float*)d_out);
}

// Round 13
// 161.533 us; speedup vs baseline: 1.2148x; 1.2148x over previous
//
#include <hip/hip_runtime.h>

#define B_   4
#define S_   2048
#define HID  512
#define H_   8
#define HD   64

typedef __attribute__((ext_vector_type(8))) short bf16x8;
typedef __attribute__((ext_vector_type(4))) float f32x4;

#define MFMA16(a, b, c) __builtin_amdgcn_mfma_f32_16x16x32_bf16(a, b, c, 0, 0, 0)

#define GAMMA_L0   (-3.4657359027997265f)
#define GAMMA_STEP (-0.3960841031771116f)

__device__ __forceinline__ void async16(const void* g, void* l) {
    __builtin_amdgcn_global_load_lds(
        (const __attribute__((address_space(1))) void*)g,
        (__attribute__((address_space(3))) void*)l, 16, 0, 0);
}

__device__ __forceinline__ unsigned short f2bf(float x) {
    unsigned u = __float_as_uint(x);
    return (unsigned short)((u + 0x7fffu + ((u >> 16) & 1u)) >> 16);
}
__device__ __forceinline__ float bfs2f(short s) {
    return __uint_as_float(((unsigned)(unsigned short)s) << 16);
}
__device__ __forceinline__ unsigned packbf(float lo, float hi) {
    return (unsigned)f2bf(lo) | ((unsigned)f2bf(hi) << 16);
}

// ---------------------------------------------------------------------------
// prep: blocks [0,2048) convert X fp32->bf16; [2048,2368) transpose weights;
// [2368,2624) xPos LUT {cos*sc, sin*sc, cos/sc, sin/sc}.
// ---------------------------------------------------------------------------
__global__ __launch_bounds__(256) void prep(
    const float* __restrict__ X,
    const float* __restrict__ Wq, const float* __restrict__ Wk,
    const float* __restrict__ Wv, const float* __restrict__ Wg,
    const float* __restrict__ Wo,
    short* __restrict__ Xb,
    short* __restrict__ WqT, short* __restrict__ WkT, short* __restrict__ WvT,
    short* __restrict__ WgT, short* __restrict__ WoT,
    float4* __restrict__ Lut)
{
    __shared__ float T[64][65];
    const int bid = blockIdx.x, t = threadIdx.x;

    if (bid < 2048) {
        size_t i = ((size_t)bid * 256 + t) * 8;
        float4 a = *(const float4*)&X[i];
        float4 b = *(const float4*)&X[i + 4];
        union { int4 v; unsigned short s[8]; } u;
        u.s[0] = f2bf(a.x); u.s[1] = f2bf(a.y); u.s[2] = f2bf(a.z); u.s[3] = f2bf(a.w);
        u.s[4] = f2bf(b.x); u.s[5] = f2bf(b.y); u.s[6] = f2bf(b.z); u.s[7] = f2bf(b.w);
        *(int4*)&Xb[i] = u.v;
        return;
    }
    if (bid >= 2368) {
        int idx = (bid - 2368) * 256 + t;   // 65536 = 2048*32
        int s = idx >> 5, k = idx & 31;
        float invf = exp2f(-0.41524101186092035f * (float)k);  // 10000^(-k/32)
        float ang  = (float)s * invf;
        float sn = sinf(ang), cs = cosf(ang);
        float sk = ((float)(2 * k) + 25.6f) / 89.6f;
        float sc = exp2f(log2f(sk) * (float)s * (1.0f / 512.0f));
        Lut[idx] = (float4){cs * sc, sn * sc, cs / sc, sn / sc};
        return;
    }

    const int wb = bid - 2048;
    const float* ip; short* op; int ild;
    if (wb < 192) {
        int which = wb >> 6, rem = wb & 63, h = rem >> 3, kt = rem & 7;
        const float* src = which == 0 ? Wq : which == 1 ? Wk : Wv;
        short* dst       = which == 0 ? WqT : which == 1 ? WkT : WvT;
        ip = src + ((size_t)h * 512 + kt * 64) * 64;
        ild = 64;
        op = dst + (size_t)(h * 64) * 512 + kt * 64;
    } else {
        int rem = wb - 192, which = rem >> 6, r3 = rem & 63, nt = r3 >> 3, kt = r3 & 7;
        const float* src = which ? Wo : Wg;
        short* dst       = which ? WoT : WgT;
        ip = src + (size_t)(kt * 64) * 512 + nt * 64;
        ild = 512;
        op = dst + (size_t)(nt * 64) * 512 + kt * 64;
    }
    {
        int r = t >> 2, c0 = (t & 3) * 16;
        #pragma unroll
        for (int e = 0; e < 4; ++e) {
            float4 f = *(const float4*)&ip[(size_t)r * ild + c0 + e * 4];
            T[r][c0 + e*4 + 0] = f.x; T[r][c0 + e*4 + 1] = f.y;
            T[r][c0 + e*4 + 2] = f.z; T[r][c0 + e*4 + 3] = f.w;
        }
    }
    __syncthreads();
    {
        int cc = t >> 2, r0 = (t & 3) * 16;
        short* orow = op + (size_t)cc * 512;
        #pragma unroll
        for (int ii = 0; ii < 8; ++ii) {
            int lo = f2bf(T[r0 + 2*ii][cc]);
            int hi = f2bf(T[r0 + 2*ii + 1][cc]);
            *(int*)(orow + r0 + 2*ii) = (lo & 0xffff) | (hi << 16);
        }
    }
}

// ---------------------------------------------------------------------------
// 64x128 bf16 MFMA GEMM core, BK=64, single buffer, XOR swizzle
// (idx&7)^(row&7). LDS: A 4096 shorts @0, B 8192 shorts @4096 = 24576 B.
// ---------------------------------------------------------------------------
__device__ __forceinline__ void stage64k(const short* __restrict__ Ag,
                                         const short* __restrict__ Bg,
                                         int k0, short* As, short* Bs, int tid)
{
    #pragma unroll
    for (int j = 0; j < 2; ++j) {          // A: 64 rows x 8 slots
        int idx = j * 256 + tid;
        int row = idx >> 3, c8 = (idx & 7) ^ (row & 7);
        async16(Ag + (size_t)row * 512 + k0 + c8 * 8, As + idx * 8);
    }
    #pragma unroll
    for (int j = 0; j < 4; ++j) {          // B: 128 rows x 8 slots
        int idx = j * 256 + tid;
        int row = idx >> 3, c8 = (idx & 7) ^ (row & 7);
        async16(Bg + (size_t)row * 512 + k0 + c8 * 8, Bs + idx * 8);
    }
}

__device__ __forceinline__ void gemm_core64(const short* __restrict__ Ag,
                                            const short* __restrict__ Bg,
                                            short* SM, f32x4 (&acc)[2][4])
{
    const int tid = threadIdx.x;
    const int L = tid & 63, quad = L >> 4, l16 = L & 15;
    const int w = tid >> 6;
    const int wrow = (w >> 1) * 32, wcol = (w & 1) * 64;
    short* As = SM;
    short* Bs = SM + 4096;

    for (int k0 = 0; k0 < 512; k0 += 64) {
        stage64k(Ag, Bg, k0, As, Bs, tid);
        __syncthreads();
        #pragma unroll
        for (int ks = 0; ks < 2; ++ks) {
            bf16x8 af[2], bfr[4];
            #pragma unroll
            for (int a = 0; a < 2; ++a) {
                int m = wrow + a * 16 + l16;
                af[a] = *(const bf16x8*)&As[m * 64 + ((quad + 4 * ks) ^ (m & 7)) * 8];
            }
            #pragma unroll
            for (int b = 0; b < 4; ++b) {
                int n = wcol + b * 16 + l16;
                bfr[b] = *(const bf16x8*)&Bs[n * 64 + ((quad + 4 * ks) ^ (n & 7)) * 8];
            }
            #pragma unroll
            for (int a = 0; a < 2; ++a)
                #pragma unroll
                for (int b = 0; b < 4; ++b)
                    acc[a][b] = MFMA16(af[a], bfr[b], acc[a][b]);
        }
        __syncthreads();
    }
}

// ---------------------------------------------------------------------------
// Fused QKV+Gate GEMM: grid (128, 16), M-tile fastest (XCD locality).
// zone = bx>>2: 0=Q (xPos+), 1=K (xPos-), 2=V, 3=Gate (SiLU).
// ---------------------------------------------------------------------------
__global__ __launch_bounds__(256) void fused_gemm(
    const short* __restrict__ Xb, const short* __restrict__ WT,
    const float4* __restrict__ Lut,
    short* __restrict__ Qb, short* __restrict__ Kb, short* __restrict__ Vb,
    short* __restrict__ Gb)
{
    __shared__ short SM[12288];   // staging 24576 B; repack 64x136 fits
    const int by = blockIdx.x;    // M-tile 0..127 (fastest)
    const int bx = blockIdx.y;    // N-tile 0..15

    f32x4 acc[2][4];
    #pragma unroll
    for (int a = 0; a < 2; ++a)
        #pragma unroll
        for (int b = 0; b < 4; ++b) acc[a][b] = (f32x4){0.f, 0.f, 0.f, 0.f};

    gemm_core64(Xb + (size_t)by * 64 * 512,
                WT + (size_t)bx * 128 * 512, SM, acc);

    const int tid = threadIdx.x, L = tid & 63, quad = L >> 4, l16 = L & 15;
    const int w = tid >> 6, wrow = (w >> 1) * 32, wcol = (w & 1) * 64;
    const int zone = bx >> 2;
    short* Out = (zone == 0) ? Qb : (zone == 1) ? Kb : Vb;

    #pragma unroll
    for (int b = 0; b < 4; ++b) {
        int ncol = (bx & 3) * 128 + wcol + b * 16 + l16;
        int d = ncol & 63, k = d >> 1;
        int colE = wcol + b * 16 + (l16 & ~1);
        #pragma unroll
        for (int a = 0; a < 2; ++a) {
            #pragma unroll
            for (int r = 0; r < 4; ++r) {
                int m = by * 64 + wrow + a * 16 + quad * 4 + r;
                int s = m & 2047;
                float v = acc[a][b][r];
                unsigned word;
                if (zone == 3) {
                    float g = v / (1.0f + __expf(-v));
                    float part = __shfl_xor(g, 1);
                    word = packbf(g, part);
                } else {
                    float part = __shfl_xor(v, 1);
                    float e = (d & 1) ? part : v;
                    float o = (d & 1) ? v : part;
                    if (zone == 2) {
                        word = packbf(e, o);
                    } else {
                        float4 f = Lut[s * 32 + k];
                        float cs = (zone == 0) ? f.x : f.z;
                        float sn = (zone == 0) ? f.y : f.w;
                        word = packbf(e * cs - o * sn, o * cs + e * sn);
                    }
                }
                if (!(l16 & 1))
                    *(int*)&SM[(wrow + a * 16 + quad * 4 + r) * 136 + colE] = word;
            }
        }
    }
    __syncthreads();
    #pragma unroll
    for (int j = 0; j < 4; ++j) {
        int idx = j * 256 + tid;
        int row = idx >> 4, c0 = (idx & 15) * 8;
        int m = by * 64 + row;
        int n = (bx & 3) * 128 + c0;
        if (zone == 3) {
            *(int4*)&Gb[(size_t)m * 512 + n] = *(const int4*)&SM[row * 136 + c0];
        } else {
            int bb = m >> 11, s = m & 2047;
            int h = n >> 6, d = n & 63;
            *(int4*)&Out[(((size_t)bb * 8 + h) * 2048 + s) * 64 + d] =
                *(const int4*)&SM[row * 136 + c0];
        }
    }
}

// ---------------------------------------------------------------------------
// Output GEMM: out = Z @ W_O, fp32 out. 64x64 tiles, BK=64, grid (128, 8):
// 1024 blocks = 4/CU assigned, all co-resident (LDS 16 KB). M-tile fastest.
// ---------------------------------------------------------------------------
__global__ __launch_bounds__(256) void out_gemm(
    const short* __restrict__ Zb, const short* __restrict__ WoT,
    float* __restrict__ Of)
{
    __shared__ short SM[8192];    // A 4096 + B 4096 shorts = 16 KB
    const int by = blockIdx.x;    // M-tile 0..127 (fastest)
    const int bx = blockIdx.y;    // N-tile 0..7

    f32x4 acc[2][2];
    #pragma unroll
    for (int a = 0; a < 2; ++a)
        #pragma unroll
        for (int b = 0; b < 2; ++b) acc[a][b] = (f32x4){0.f, 0.f, 0.f, 0.f};

    const int tid = threadIdx.x;
    const int L = tid & 63, quad = L >> 4, l16 = L & 15;
    const int w = tid >> 6;
    const int wrow = (w >> 1) * 32, wcol = (w & 1) * 32;
    const short* Ag = Zb + (size_t)by * 64 * 512;
    const short* Bg = WoT + (size_t)bx * 64 * 512;
    short* As = SM;
    short* Bs = SM + 4096;

    for (int k0 = 0; k0 < 512; k0 += 64) {
        #pragma unroll
        for (int j = 0; j < 2; ++j) {
            int idx = j * 256 + tid;
            int row = idx >> 3, c8 = (idx & 7) ^ (row & 7);
            async16(Ag + (size_t)row * 512 + k0 + c8 * 8, As + idx * 8);
            async16(Bg + (size_t)row * 512 + k0 + c8 * 8, Bs + idx * 8);
        }
        __syncthreads();
        #pragma unroll
        for (int ks = 0; ks < 2; ++ks) {
            bf16x8 af[2], bfr[2];
            #pragma unroll
            for (int a = 0; a < 2; ++a) {
                int m = wrow + a * 16 + l16;
                af[a] = *(const bf16x8*)&As[m * 64 + ((quad + 4 * ks) ^ (m & 7)) * 8];
            }
            #pragma unroll
            for (int b = 0; b < 2; ++b) {
                int n = wcol + b * 16 + l16;
                bfr[b] = *(const bf16x8*)&Bs[n * 64 + ((quad + 4 * ks) ^ (n & 7)) * 8];
            }
            #pragma unroll
            for (int a = 0; a < 2; ++a)
                #pragma unroll
                for (int b = 0; b < 2; ++b)
                    acc[a][b] = MFMA16(af[a], bfr[b], acc[a][b]);
        }
        __syncthreads();
    }

    #pragma unroll
    for (int b = 0; b < 2; ++b) {
        int ncol = bx * 64 + wcol + b * 16 + l16;
        #pragma unroll
        for (int a = 0; a < 2; ++a)
            #pragma unroll
            for (int r = 0; r < 4; ++r) {
                int m = by * 64 + wrow + a * 16 + quad * 4 + r;
                Of[(size_t)m * 512 + ncol] = acc[a][b][r];
            }
    }
}

// ---------------------------------------------------------------------------
// Retention R1: Gt[bn][c][d_v][d_k] = sum_j gamma^(64-jl) V[j][d_v] K[j][d_k]
// grid (32 c, 32 bn) — 1024 parallel blocks.
// ---------------------------------------------------------------------------
__global__ __launch_bounds__(256) void ret_g(
    const short* __restrict__ Kb, const short* __restrict__ Vb,
    short* __restrict__ Gt)
{
    __shared__ short Kt[64 * 72];
    __shared__ short Vt[64 * 72];
    const int tid = threadIdx.x, L = tid & 63, quad = L >> 4, l16 = L & 15;
    const int w = tid >> 6;
    const int c = blockIdx.x, bn = blockIdx.y, hh = bn & 7;

    float gamma = 1.0f - expf(GAMMA_L0 + GAMMA_STEP * (float)hh);
    float lg = log2f(gamma);

    {
        const short* kg = Kb + ((size_t)bn * 2048 + c * 64 + L) * 64 + w * 16;
        const short* vg = Vb + ((size_t)bn * 2048 + c * 64 + L) * 64 + w * 16;
        float wgt = exp2f(lg * (float)(64 - L));
        int4 k0 = *(const int4*)kg; int4 k1 = *(const int4*)(kg + 8);
        int4 v0 = *(const int4*)vg; int4 v1 = *(const int4*)(vg + 8);
        short* kt = Kt + L; short* vt = Vt + L;
        #pragma unroll
        for (int q = 0; q < 4; ++q) {
            int uk = ((const int*)&k0)[q];
            kt[(w*16 + 2*q)     * 72] = (short)f2bf(bfs2f((short)uk) * wgt);
            kt[(w*16 + 2*q + 1) * 72] = (short)f2bf(bfs2f((short)(uk >> 16)) * wgt);
            int uv = ((const int*)&v0)[q];
            vt[(w*16 + 2*q)     * 72] = (short)uv;
            vt[(w*16 + 2*q + 1) * 72] = (short)(uv >> 16);
        }
        #pragma unroll
        for (int q = 0; q < 4; ++q) {
            int uk = ((const int*)&k1)[q];
            kt[(w*16 + 8 + 2*q) * 72] = (short)f2bf(bfs2f((short)uk) * wgt);
            kt[(w*16 + 9 + 2*q) * 72] = (short)f2bf(bfs2f((short)(uk >> 16)) * wgt);
            int uv = ((const int*)&v1)[q];
            vt[(w*16 + 8 + 2*q) * 72] = (short)uv;
            vt[(w*16 + 9 + 2*q) * 72] = (short)(uv >> 16);
        }
    }
    __syncthreads();

    bf16x8 a0 = *(const bf16x8*)&Vt[(w * 16 + l16) * 72 + quad * 8];
    bf16x8 a1 = *(const bf16x8*)&Vt[(w * 16 + l16) * 72 + 32 + quad * 8];
    short* Gp = Gt + ((size_t)bn * 32 + c) * 4096;
    #pragma unroll
    for (int b = 0; b < 4; ++b) {
        bf16x8 b0 = *(const bf16x8*)&Kt[(b * 16 + l16) * 72 + quad * 8];
        bf16x8 b1 = *(const bf16x8*)&Kt[(b * 16 + l16) * 72 + 32 + quad * 8];
        f32x4 acc = (f32x4){0.f, 0.f, 0.f, 0.f};
        acc = MFMA16(a0, b0, acc);
        acc = MFMA16(a1, b1, acc);
        #pragma unroll
        for (int r = 0; r < 4; ++r) {
            float v = acc[r];
            float part = __shfl_xor(v, 1);
            unsigned word = packbf(v, part);
            if (!(l16 & 1))
                *(int*)&Gp[(w*16 + quad*4 + r) * 64 + b * 16 + (l16 & ~1)] = word;
        }
    }
}

// ---------------------------------------------------------------------------
// Retention R2: in-place decay scan. buffer[c] <- M_c; M_{c+1}=g64*M_c+G_c.
// grid (4, 32) — elementwise over the 4096 state entries per bn.
// ---------------------------------------------------------------------------
__global__ __launch_bounds__(256) void ret_scan(short* __restrict__ GM)
{
    const int tid = threadIdx.x, seg = blockIdx.x, bn = blockIdx.y, hh = bn & 7;
    float gamma = 1.0f - expf(GAMMA_L0 + GAMMA_STEP * (float)hh);
    float g64 = exp2f(log2f(gamma) * 64.0f);

    size_t base = (size_t)bn * 32 * 4096 + seg * 1024 + tid * 4;
    float m0 = 0.f, m1 = 0.f, m2 = 0.f, m3 = 0.f;
    #pragma unroll 4
    for (int c = 0; c < 32; ++c) {
        int2* p = (int2*)&GM[base + (size_t)c * 4096];
        int2 g = *p;
        *p = make_int2((int)packbf(m0, m1), (int)packbf(m2, m3));
        m0 = g64 * m0 + bfs2f((short)g.x);
        m1 = g64 * m1 + bfs2f((short)(g.x >> 16));
        m2 = g64 * m2 + bfs2f((short)g.y);
        m3 = g64 * m3 + bfs2f((short)(g.y >> 16));
    }
}

// ---------------------------------------------------------------------------
// Retention main + fused GroupNorm/gate:
//   Y = (QK^T . gamma^|i-j|) V + gamma^il (Q M_c)   [fp32 in regs]
//   Z = silu_gate * ((Y - mu)/sqrt(var+eps) * gw + gb)   -> Zb bf16 [8192][512]
// ---------------------------------------------------------------------------
__global__ __launch_bounds__(256) void ret_main(
    const short* __restrict__ Qb, const short* __restrict__ Kb,
    const short* __restrict__ Vb, const short* __restrict__ Mb,
    const short* __restrict__ Gb,
    const float* __restrict__ gw, const float* __restrict__ gb,
    short* __restrict__ Zb)
{
    __shared__ short Qs[4096];
    __shared__ short Ks[4096];
    __shared__ short Ms[4096];
    __shared__ short Vt[64 * 72];
    __shared__ short Pw[4][16 * 72];

    const int tid = threadIdx.x, L = tid & 63, quad = L >> 4, l16 = L & 15;
    const int w = tid >> 6;
    const int c = blockIdx.x, bn = blockIdx.y, hh = bn & 7, bb = bn >> 3;

    float gamma = 1.0f - expf(GAMMA_L0 + GAMMA_STEP * (float)hh);
    float lg = log2f(gamma);

    float Dabs[4][4];
    #pragma unroll
    for (int b = 0; b < 4; ++b)
        #pragma unroll
        for (int r = 0; r < 4; ++r) {
            int dlt = (w * 16 + quad * 4 + r) - (b * 16 + l16);
            Dabs[b][r] = exp2f(lg * fabsf((float)dlt));
        }
    float gq[4];
    #pragma unroll
    for (int r = 0; r < 4; ++r)
        gq[r] = exp2f(lg * (float)(w * 16 + quad * 4 + r));

    {
        const short* qg = Qb + ((size_t)bn * 2048 + c * 64 + w * 16 + (L >> 2)) * 64 + (L & 3) * 8;
        async16(qg,      Qs + w * 512 + L * 8);
        async16(qg + 32, Qs + 2048 + w * 512 + L * 8);
        const short* kg = Kb + ((size_t)bn * 2048 + c * 64 + w * 16 + (L >> 2)) * 64 + (L & 3) * 8;
        async16(kg,      Ks + w * 512 + L * 8);
        async16(kg + 32, Ks + 2048 + w * 512 + L * 8);
        const short* mg = Mb + ((size_t)bn * 32 + c) * 4096 + (w * 16 + (L >> 2)) * 64 + (L & 3) * 8;
        async16(mg,      Ms + w * 512 + L * 8);
        async16(mg + 32, Ms + 2048 + w * 512 + L * 8);
    }
    {
        const short* vg = Vb + ((size_t)bn * 2048 + c * 64 + L) * 64 + w * 16;
        int4 v0 = *(const int4*)vg;
        int4 v1 = *(const int4*)(vg + 8);
        short* vt = Vt + L;
        #pragma unroll
        for (int q = 0; q < 4; ++q) {
            int u = ((const int*)&v0)[q];
            vt[(w*16 + 2*q)     * 72] = (short)u;
            vt[(w*16 + 2*q + 1) * 72] = (short)(u >> 16);
        }
        #pragma unroll
        for (int q = 0; q < 4; ++q) {
            int u = ((const int*)&v1)[q];
            vt[(w*16 + 8 + 2*q) * 72] = (short)u;
            vt[(w*16 + 9 + 2*q) * 72] = (short)(u >> 16);
        }
    }
    __syncthreads();

    bf16x8 aQ0 = *(const bf16x8*)&Qs[(w * 16 + l16) * 32 + quad * 8];
    bf16x8 aQ1 = *(const bf16x8*)&Qs[2048 + (w * 16 + l16) * 32 + quad * 8];
    f32x4 accM[4];
    #pragma unroll
    for (int b = 0; b < 4; ++b) {
        bf16x8 k0 = *(const bf16x8*)&Ks[(b * 16 + l16) * 32 + quad * 8];
        bf16x8 k1 = *(const bf16x8*)&Ks[2048 + (b * 16 + l16) * 32 + quad * 8];
        f32x4 S = (f32x4){0.f, 0.f, 0.f, 0.f};
        S = MFMA16(aQ0, k0, S);
        S = MFMA16(aQ1, k1, S);
        #pragma unroll
        for (int r = 0; r < 4; ++r)
            Pw[w][(quad * 4 + r) * 72 + b * 16 + l16] = (short)f2bf(S[r] * Dabs[b][r]);

        bf16x8 m0 = *(const bf16x8*)&Ms[(b * 16 + l16) * 32 + quad * 8];
        bf16x8 m1 = *(const bf16x8*)&Ms[2048 + (b * 16 + l16) * 32 + quad * 8];
        f32x4 Mv = (f32x4){0.f, 0.f, 0.f, 0.f};
        Mv = MFMA16(aQ0, m0, Mv);
        Mv = MFMA16(aQ1, m1, Mv);
        accM[b] = Mv;
    }

    bf16x8 aP0 = *(const bf16x8*)&Pw[w][l16 * 72 + quad * 8];
    bf16x8 aP1 = *(const bf16x8*)&Pw[w][l16 * 72 + 32 + quad * 8];
    f32x4 Y4[4];
    #pragma unroll
    for (int b2 = 0; b2 < 4; ++b2) {
        bf16x8 v0f = *(const bf16x8*)&Vt[(b2 * 16 + l16) * 72 + quad * 8];
        bf16x8 v1f = *(const bf16x8*)&Vt[(b2 * 16 + l16) * 72 + 32 + quad * 8];
        f32x4 yv = (f32x4){0.f, 0.f, 0.f, 0.f};
        yv = MFMA16(aP0, v0f, yv);
        yv = MFMA16(aP1, v1f, yv);
        #pragma unroll
        for (int r = 0; r < 4; ++r)
            Y4[b2][r] = yv[r] + gq[r] * accM[b2][r];
    }

    #pragma unroll
    for (int r = 0; r < 4; ++r) {
        float s1 = 0.f, s2 = 0.f;
        #pragma unroll
        for (int b2 = 0; b2 < 4; ++b2) {
            float v = Y4[b2][r];
            s1 += v; s2 += v * v;
        }
        #pragma unroll
        for (int off = 1; off < 16; off <<= 1) {
            s1 += __shfl_xor(s1, off);
            s2 += __shfl_xor(s2, off);
        }
        float mu = s1 * (1.0f / 64.0f);
        float var = s2 * (1.0f / 64.0f) - mu * mu;
        float rstd = rsqrtf(var + 1e-5f);

        int il = w * 16 + quad * 4 + r;
        size_t row = (size_t)bb * 2048 + c * 64 + il;
        #pragma unroll
        for (int b2 = 0; b2 < 4; ++b2) {
            int j = hh * 64 + b2 * 16 + l16;
            float yn = (Y4[b2][r] - mu) * rstd * gw[j] + gb[j];
            float z = bfs2f(Gb[row * 512 + j]) * yn;
            float part = __shfl_xor(z, 1);
            if (!(l16 & 1))
                *(int*)&Zb[row * 512 + hh * 64 + b2 * 16 + (l16 & ~1)] = packbf(z, part);
        }
    }
}

// ---------------------------------------------------------------------------
extern "C" void kernel_launch(void* const* d_in, const int* in_sizes, int n_in,
                              void* d_out, int out_size, void* d_ws, size_t ws_size,
                              hipStream_t stream)
{
    const float* X  = (const float*)d_in[0];
    const float* Wq = (const float*)d_in[1];
    const float* Wk = (const float*)d_in[2];
    const float* Wv = (const float*)d_in[3];
    const float* Wg = (const float*)d_in[4];
    const float* Wo = (const float*)d_in[5];
    const float* gw = (const float*)d_in[6];
    const float* gb = (const float*)d_in[7];

    char* ws = (char*)d_ws;
    short* Xb  = (short*)ws;                          // 8,388,608 B
    short* WqT = (short*)(ws + 8388608);              // 512 KB each: Q,K,V,G,O
    short* WkT = WqT + 262144;
    short* WvT = WkT + 262144;
    short* WgT = WvT + 262144;
    short* WoT = WgT + 262144;
    short* Qb  = (short*)(ws + 11010048);             // 8,388,608 B each
    short* Kb  = Qb + 4194304;
    short* Vb  = Kb + 4194304;
    float4* Lut = (float4*)(ws + 36175872);           // 1,048,576 B
    short* GM  = (short*)(ws + 37224448);             // 8,388,608 B (Gt -> M in-place)
    short* Zb  = (short*)(ws + 45613056);             // 8,388,608 B
    short* Gb  = (short*)(ws + 54001664);             // 8,388,608 B (ends 62,390,272)

    prep<<<2624, 256, 0, stream>>>(X, Wq, Wk, Wv, Wg, Wo,
                                   Xb, WqT, WkT, WvT, WgT, WoT, Lut);
    fused_gemm<<<dim3(128, 16), 256, 0, stream>>>(Xb, WqT, Lut, Qb, Kb, Vb, Gb);
    ret_g<<<dim3(32, 32), 256, 0, stream>>>(Kb, Vb, GM);
    ret_scan<<<dim3(4, 32), 256, 0, stream>>>(GM);
    ret_main<<<dim3(32, 32), 256, 0, stream>>>(Qb, Kb, Vb, GM, Gb, gw, gb, Zb);
    out_gemm<<<dim3(128, 8), 256, 0, stream>>>(Zb, WoT, (float*)d_out);
}